// Round 1
// baseline (248.720 us; speedup 1.0000x reference)
//
#include <hip/hip_runtime.h>
#include <stdint.h>

#define B_ 8
#define S_ 512
#define D_ 1024
#define H_ 16
#define DK_ 64

typedef float f32x4 __attribute__((ext_vector_type(4)));
typedef float float4v __attribute__((ext_vector_type(4)));
typedef short bf16x8 __attribute__((ext_vector_type(8)));
typedef short short4v __attribute__((ext_vector_type(4)));
typedef __bf16 bfv8 __attribute__((ext_vector_type(8)));

__device__ __forceinline__ short f2bf(float f) {
    uint32_t u = __builtin_bit_cast(uint32_t, f);
    u += 0x7FFFu + ((u >> 16) & 1u);
    return (short)(uint16_t)(u >> 16);
}

__device__ __forceinline__ f32x4 mfma_bf16(bf16x8 a, bf16x8 b, f32x4 c) {
    return __builtin_amdgcn_mfma_f32_16x16x32_bf16(
        __builtin_bit_cast(bfv8, a), __builtin_bit_cast(bfv8, b), c, 0, 0, 0);
}

__device__ __forceinline__ bf16x8 pack8(float4v a, float4v b) {
    bf16x8 v;
    v[0] = f2bf(a[0]); v[1] = f2bf(a[1]); v[2] = f2bf(a[2]); v[3] = f2bf(a[3]);
    v[4] = f2bf(b[0]); v[5] = f2bf(b[1]); v[6] = f2bf(b[2]); v[7] = f2bf(b[3]);
    return v;
}

// ---------------------------------------------------------------------------
// comb[b,q,k] = mask ? -1e9 : w1*exp(-dist) + w2*adj + b0
// ---------------------------------------------------------------------------
__global__ __launch_bounds__(256) void precomp_kernel(
    const int* __restrict__ mask, const float* __restrict__ adj,
    const float* __restrict__ dist, const float* __restrict__ cw,
    const float* __restrict__ cb, float* __restrict__ comb, int n)
{
    const float w1 = cw[1], w2 = cw[2], b0 = cb[0];
    for (int i = blockIdx.x * 256 + threadIdx.x; i < n; i += gridDim.x * 256) {
        float c = -1e9f;
        if (mask[i] == 0) c = fmaf(w2, adj[i], fmaf(w1, __expf(-dist[i]), b0));
        comb[i] = c;
    }
}

// ---------------------------------------------------------------------------
// Projection GEMM: C[m,n] = sum_d X[m,d] * W[n,d]   (M=4096, N=1024, K=1024)
// z = 0 -> Qp [b,h,s,dk] bf16, z = 1 -> Kp [b,h,s,dk] bf16,
// z = 2 -> VpT [b,h,dk,s] bf16 (transposed for PV B-fragments)
// 128x128 tile, BK=64, 4 waves (2x2), reg-staged LDS w/ fp32->bf16 convert,
// T2 XOR swizzle on LDS chunks.
// ---------------------------------------------------------------------------
__global__ __launch_bounds__(256) void proj_qkv_kernel(
    const float* __restrict__ xq, const float* __restrict__ xk, const float* __restrict__ xv,
    const float* __restrict__ wqp, const float* __restrict__ wkp, const float* __restrict__ wvp,
    short* __restrict__ Qp, short* __restrict__ Kp, short* __restrict__ VpT)
{
    __shared__ __align__(16) short Alds[128 * 64];
    __shared__ __align__(16) short Blds[128 * 64];

    const int z = blockIdx.z;
    const float* X = (z == 0) ? xq : (z == 1) ? xk : xv;
    const float* W = (z == 0) ? wqp : (z == 1) ? wkp : wvp;

    const int tid = threadIdx.x;
    const int lane = tid & 63, wid = tid >> 6;
    const int l15 = lane & 15, lg = lane >> 4;
    const int m0 = blockIdx.y * 128, n0 = blockIdx.x * 128;
    const int wm = wid >> 1, wn = wid & 1;

    f32x4 acc[4][4] = {};

    for (int k0 = 0; k0 < D_; k0 += 64) {
        #pragma unroll
        for (int g = 0; g < 4; ++g) {
            const int c = g * 256 + tid;
            const int row = c >> 3, cc = c & 7;
            const int swc = cc ^ (row & 7);
            const float* ga = X + (size_t)(m0 + row) * D_ + k0 + cc * 8;
            float4v a0 = *(const float4v*)ga;
            float4v a1 = *(const float4v*)(ga + 4);
            *(bf16x8*)&Alds[(row * 8 + swc) * 8] = pack8(a0, a1);
            const float* gb = W + (size_t)(n0 + row) * D_ + k0 + cc * 8;
            float4v b0v = *(const float4v*)gb;
            float4v b1v = *(const float4v*)(gb + 4);
            *(bf16x8*)&Blds[(row * 8 + swc) * 8] = pack8(b0v, b1v);
        }
        __syncthreads();
        #pragma unroll
        for (int ks = 0; ks < 2; ++ks) {
            bf16x8 af[4], bfr[4];
            #pragma unroll
            for (int i = 0; i < 4; ++i) {
                const int row = wm * 64 + i * 16 + l15;
                af[i] = *(const bf16x8*)&Alds[(row * 8 + ((ks * 4 + lg) ^ (row & 7))) * 8];
            }
            #pragma unroll
            for (int j = 0; j < 4; ++j) {
                const int row = wn * 64 + j * 16 + l15;
                bfr[j] = *(const bf16x8*)&Blds[(row * 8 + ((ks * 4 + lg) ^ (row & 7))) * 8];
            }
            #pragma unroll
            for (int i = 0; i < 4; ++i)
                #pragma unroll
                for (int j = 0; j < 4; ++j)
                    acc[i][j] = mfma_bf16(af[i], bfr[j], acc[i][j]);
        }
        __syncthreads();
    }

    // Epilogue. C/D fragment: col = lane&15, row = (lane>>4)*4 + reg.
    if (z < 2) {
        short* Outp = (z == 0) ? Qp : Kp;
        #pragma unroll
        for (int i = 0; i < 4; ++i) {
            #pragma unroll
            for (int j = 0; j < 4; ++j) {
                const int n = n0 + wn * 64 + j * 16 + l15;
                const int h = n >> 6, dk = n & 63;
                #pragma unroll
                for (int r = 0; r < 4; ++r) {
                    const int m = m0 + wm * 64 + i * 16 + lg * 4 + r;
                    const int b = m >> 9, s = m & 511;
                    Outp[((size_t)(b * H_ + h) * S_ + s) * DK_ + dk] = f2bf(acc[i][j][r]);
                }
            }
        }
    } else {
        #pragma unroll
        for (int i = 0; i < 4; ++i) {
            const int mb = m0 + wm * 64 + i * 16 + lg * 4;
            const int b = mb >> 9, s0v = mb & 511;
            #pragma unroll
            for (int j = 0; j < 4; ++j) {
                const int n = n0 + wn * 64 + j * 16 + l15;
                const int h = n >> 6, dk = n & 63;
                short4v v;
                #pragma unroll
                for (int r = 0; r < 4; ++r) v[r] = f2bf(acc[i][j][r]);
                *(short4v*)&VpT[((size_t)(b * H_ + h) * DK_ + dk) * S_ + s0v] = v;
            }
        }
    }
}

// ---------------------------------------------------------------------------
// Fused attention. One wave per 16 q-rows per (b,h). Full 512-wide score row
// in registers (32 x f32x4). Two in-register softmaxes (16-lane shfl_xor
// reductions), attn written fp32 to d_out, P transposed via 4KB swizzled
// per-wave LDS chunk into MFMA A-fragments, context accumulated and written
// bf16 to Ctx [b,s,h*64+dk].
// ---------------------------------------------------------------------------
__global__ __launch_bounds__(64, 2) void attn_kernel(
    const short* __restrict__ Qp, const short* __restrict__ Kp,
    const short* __restrict__ VpT, const float* __restrict__ comb,
    const float* __restrict__ cw, float* __restrict__ attn_out,
    short* __restrict__ Ctx)
{
    __shared__ __align__(16) short plds[16 * 128];

    const int lane = threadIdx.x;
    const int l15 = lane & 15, lg = lane >> 4;
    const int qt = blockIdx.x, h = blockIdx.y, b = blockIdx.z;
    const int bh = b * H_ + h;
    const int q0 = qt * 16;

    const short* Qb = Qp + (size_t)bh * S_ * DK_;
    const short* Kb = Kp + (size_t)bh * S_ * DK_;
    const short* Vb = VpT + (size_t)bh * DK_ * S_;
    const float* cbm = comb + (size_t)b * S_ * S_ + (size_t)q0 * S_;
    const float w0 = cw[0];

    // Q A-fragments (rows = q, contiguous dk)
    bf16x8 aq0 = *(const bf16x8*)(Qb + (q0 + l15) * DK_ + lg * 8);
    bf16x8 aq1 = *(const bf16x8*)(Qb + (q0 + l15) * DK_ + 32 + lg * 8);

    // scores: sc[nf] holds D rows q = lg*4+r, col k = nf*16 + l15
    f32x4 sc[32];
    #pragma unroll
    for (int nf = 0; nf < 32; ++nf) {
        bf16x8 bk0 = *(const bf16x8*)(Kb + (size_t)(nf * 16 + l15) * DK_ + lg * 8);
        bf16x8 bk1 = *(const bf16x8*)(Kb + (size_t)(nf * 16 + l15) * DK_ + 32 + lg * 8);
        f32x4 a = {};
        a = mfma_bf16(aq0, bk0, a);
        a = mfma_bf16(aq1, bk1, a);
        sc[nf] = a;
    }

    // pass A: scale + mask, row max
    f32x4 mx;
    mx[0] = mx[1] = mx[2] = mx[3] = -3e38f;
    #pragma unroll
    for (int nf = 0; nf < 32; ++nf) {
        const int k = nf * 16 + l15;
        #pragma unroll
        for (int r = 0; r < 4; ++r) {
            const float c = cbm[(size_t)(lg * 4 + r) * S_ + k];
            const float v = (c < -1e8f) ? -1e9f : sc[nf][r] * 0.125f;
            sc[nf][r] = v;
            mx[r] = fmaxf(mx[r], v);
        }
    }
    #pragma unroll
    for (int off = 1; off < 16; off <<= 1)
        #pragma unroll
        for (int r = 0; r < 4; ++r)
            mx[r] = fmaxf(mx[r], __shfl_xor(mx[r], off));

    // pass B: exp + row sum  -> softmax-1
    f32x4 sm = {};
    #pragma unroll
    for (int nf = 0; nf < 32; ++nf)
        #pragma unroll
        for (int r = 0; r < 4; ++r) {
            const float e = __expf(sc[nf][r] - mx[r]);
            sc[nf][r] = e;
            sm[r] += e;
        }
    #pragma unroll
    for (int off = 1; off < 16; off <<= 1)
        #pragma unroll
        for (int r = 0; r < 4; ++r)
            sm[r] += __shfl_xor(sm[r], off);
    f32x4 rs1;
    #pragma unroll
    for (int r = 0; r < 4; ++r) rs1[r] = 1.0f / sm[r];

    // pass C: weighted = w0*p + comb  (masked: p==0 exactly -> w == -1e9), max
    f32x4 mx2;
    mx2[0] = mx2[1] = mx2[2] = mx2[3] = -3e38f;
    #pragma unroll
    for (int nf = 0; nf < 32; ++nf) {
        const int k = nf * 16 + l15;
        #pragma unroll
        for (int r = 0; r < 4; ++r) {
            const float c = cbm[(size_t)(lg * 4 + r) * S_ + k];
            const float p = sc[nf][r] * rs1[r];
            const float w = fmaf(w0, p, c);
            sc[nf][r] = w;
            mx2[r] = fmaxf(mx2[r], w);
        }
    }
    #pragma unroll
    for (int off = 1; off < 16; off <<= 1)
        #pragma unroll
        for (int r = 0; r < 4; ++r)
            mx2[r] = fmaxf(mx2[r], __shfl_xor(mx2[r], off));

    // pass D: exp + row sum -> softmax-2
    f32x4 sm2 = {};
    #pragma unroll
    for (int nf = 0; nf < 32; ++nf)
        #pragma unroll
        for (int r = 0; r < 4; ++r) {
            const float e = __expf(sc[nf][r] - mx2[r]);
            sc[nf][r] = e;
            sm2[r] += e;
        }
    #pragma unroll
    for (int off = 1; off < 16; off <<= 1)
        #pragma unroll
        for (int r = 0; r < 4; ++r)
            sm2[r] += __shfl_xor(sm2[r], off);
    f32x4 rs2;
    #pragma unroll
    for (int r = 0; r < 4; ++r) rs2[r] = 1.0f / sm2[r];

    // pass E: per 128-k chunk: write attn (fp32), stage P (bf16, swizzled LDS),
    // PV MFMA with B-fragments streamed from VpT.
    float* aout = attn_out + ((size_t)bh * S_ + q0) * S_;
    f32x4 cacc[4] = {};
    #pragma unroll
    for (int ch = 0; ch < 4; ++ch) {
        #pragma unroll
        for (int nl = 0; nl < 8; ++nl) {
            const int nf = ch * 8 + nl;
            const int k = nf * 16 + l15;
            #pragma unroll
            for (int r = 0; r < 4; ++r) {
                const int q = lg * 4 + r;
                const float av = sc[nf][r] * rs2[r];
                aout[(size_t)q * S_ + k] = av;
                const int byteo = (q * 256 + (nl * 16 + l15) * 2) ^ ((q & 7) << 4);
                *(short*)((char*)plds + byteo) = f2bf(av);
            }
        }
        #pragma unroll
        for (int ks = 0; ks < 4; ++ks) {
            const int byteA = (l15 * 256 + (ks * 32 + lg * 8) * 2) ^ ((l15 & 7) << 4);
            bf16x8 pa = *(const bf16x8*)((char*)plds + byteA);
            #pragma unroll
            for (int j = 0; j < 4; ++j) {
                bf16x8 bv = *(const bf16x8*)(Vb + (size_t)(j * 16 + l15) * S_ + ch * 128 + ks * 32 + lg * 8);
                cacc[j] = mfma_bf16(pa, bv, cacc[j]);
            }
        }
    }

    #pragma unroll
    for (int j = 0; j < 4; ++j)
        #pragma unroll
        for (int r = 0; r < 4; ++r) {
            const int q = q0 + lg * 4 + r;
            const int d = h * DK_ + j * 16 + l15;
            Ctx[(size_t)(b * S_ + q) * D_ + d] = f2bf(cacc[j][r]);
        }
}

// ---------------------------------------------------------------------------
// Output GEMM: Out[m,n] = sum_d Ctx[m,d] * Wfc[n,d], Ctx bf16, Out fp32.
// ---------------------------------------------------------------------------
__global__ __launch_bounds__(256) void fc_kernel(
    const short* __restrict__ Ctx, const float* __restrict__ Wfc,
    float* __restrict__ Out)
{
    __shared__ __align__(16) short Alds[128 * 64];
    __shared__ __align__(16) short Blds[128 * 64];

    const int tid = threadIdx.x;
    const int lane = tid & 63, wid = tid >> 6;
    const int l15 = lane & 15, lg = lane >> 4;
    const int m0 = blockIdx.y * 128, n0 = blockIdx.x * 128;
    const int wm = wid >> 1, wn = wid & 1;

    f32x4 acc[4][4] = {};

    for (int k0 = 0; k0 < D_; k0 += 64) {
        #pragma unroll
        for (int g = 0; g < 4; ++g) {
            const int c = g * 256 + tid;
            const int row = c >> 3, cc = c & 7;
            const int swc = cc ^ (row & 7);
            bf16x8 va = *(const bf16x8*)(Ctx + (size_t)(m0 + row) * D_ + k0 + cc * 8);
            *(bf16x8*)&Alds[(row * 8 + swc) * 8] = va;
            const float* gb = Wfc + (size_t)(n0 + row) * D_ + k0 + cc * 8;
            float4v b0v = *(const float4v*)gb;
            float4v b1v = *(const float4v*)(gb + 4);
            *(bf16x8*)&Blds[(row * 8 + swc) * 8] = pack8(b0v, b1v);
        }
        __syncthreads();
        #pragma unroll
        for (int ks = 0; ks < 2; ++ks) {
            bf16x8 af[4], bfr[4];
            #pragma unroll
            for (int i = 0; i < 4; ++i) {
                const int row = wm * 64 + i * 16 + l15;
                af[i] = *(const bf16x8*)&Alds[(row * 8 + ((ks * 4 + lg) ^ (row & 7))) * 8];
            }
            #pragma unroll
            for (int j = 0; j < 4; ++j) {
                const int row = wn * 64 + j * 16 + l15;
                bfr[j] = *(const bf16x8*)&Blds[(row * 8 + ((ks * 4 + lg) ^ (row & 7))) * 8];
            }
            #pragma unroll
            for (int i = 0; i < 4; ++i)
                #pragma unroll
                for (int j = 0; j < 4; ++j)
                    acc[i][j] = mfma_bf16(af[i], bfr[j], acc[i][j]);
        }
        __syncthreads();
    }

    #pragma unroll
    for (int i = 0; i < 4; ++i)
        #pragma unroll
        for (int j = 0; j < 4; ++j)
            #pragma unroll
            for (int r = 0; r < 4; ++r) {
                const int m = m0 + wm * 64 + i * 16 + lg * 4 + r;
                const int n = n0 + wn * 64 + j * 16 + l15;
                Out[(size_t)m * D_ + n] = acc[i][j][r];
            }
}

// ---------------------------------------------------------------------------
extern "C" void kernel_launch(void* const* d_in, const int* in_sizes, int n_in,
                              void* d_out, int out_size, void* d_ws, size_t ws_size,
                              hipStream_t stream) {
    const float* xq   = (const float*)d_in[0];
    const float* xk   = (const float*)d_in[1];
    const float* xv   = (const float*)d_in[2];
    const int*   mask = (const int*)d_in[3];
    const float* adj  = (const float*)d_in[4];
    const float* dist = (const float*)d_in[5];
    const float* wq   = (const float*)d_in[6];
    const float* wk   = (const float*)d_in[7];
    const float* wv   = (const float*)d_in[8];
    const float* wfc  = (const float*)d_in[9];
    const float* cw   = (const float*)d_in[10];
    const float* cb   = (const float*)d_in[11];

    float* out  = (float*)d_out;                       // (B,S,D) fp32
    float* attn = out + (size_t)B_ * S_ * D_;          // (B,H,S,S) fp32

    char* ws = (char*)d_ws;
    short* Qp   = (short*)(ws);                        // [B,H,S,DK] bf16, 8 MiB
    short* Kp   = (short*)(ws + (8u  << 20));          // [B,H,S,DK] bf16, 8 MiB
    short* VpT  = (short*)(ws + (16u << 20));          // [B,H,DK,S] bf16, 8 MiB
    short* Ctx  = (short*)(ws + (24u << 20));          // [B*S, D]   bf16, 8 MiB
    float* comb = (float*)(ws + (32u << 20));          // [B,S,S]    fp32, 8 MiB

    precomp_kernel<<<dim3(1024), dim3(256), 0, stream>>>(
        mask, adj, dist, cw, cb, comb, B_ * S_ * S_);
    proj_qkv_kernel<<<dim3(8, 32, 3), dim3(256), 0, stream>>>(
        xq, xk, xv, wq, wk, wv, Qp, Kp, VpT);
    attn_kernel<<<dim3(32, 16, 8), dim3(64), 0, stream>>>(
        Qp, Kp, VpT, comb, cw, attn, Ctx);
    fc_kernel<<<dim3(8, 32), dim3(256), 0, stream>>>(Ctx, wfc, out);
}

// Round 2
// 213.180 us; speedup vs baseline: 1.1667x; 1.1667x over previous
//
#include <hip/hip_runtime.h>
#include <stdint.h>

#define B_ 8
#define S_ 512
#define D_ 1024
#define H_ 16
#define DK_ 64

typedef float f32x4 __attribute__((ext_vector_type(4)));
typedef float float4v __attribute__((ext_vector_type(4)));
typedef short bf16x8 __attribute__((ext_vector_type(8)));
typedef short short4v __attribute__((ext_vector_type(4)));
typedef __bf16 bfv8 __attribute__((ext_vector_type(8)));

__device__ __forceinline__ short f2bf(float f) {
    uint32_t u = __builtin_bit_cast(uint32_t, f);
    u += 0x7FFFu + ((u >> 16) & 1u);
    return (short)(uint16_t)(u >> 16);
}

__device__ __forceinline__ f32x4 mfma_bf16(bf16x8 a, bf16x8 b, f32x4 c) {
    return __builtin_amdgcn_mfma_f32_16x16x32_bf16(
        __builtin_bit_cast(bfv8, a), __builtin_bit_cast(bfv8, b), c, 0, 0, 0);
}

__device__ __forceinline__ bf16x8 pack8(float4v a, float4v b) {
    bf16x8 v;
    v[0] = f2bf(a[0]); v[1] = f2bf(a[1]); v[2] = f2bf(a[2]); v[3] = f2bf(a[3]);
    v[4] = f2bf(b[0]); v[5] = f2bf(b[1]); v[6] = f2bf(b[2]); v[7] = f2bf(b[3]);
    return v;
}

// ---------------------------------------------------------------------------
// comb[b,q,k] = mask ? -1e9 : w1*exp(-dist) + w2*adj + b0
// ---------------------------------------------------------------------------
__global__ __launch_bounds__(256) void precomp_kernel(
    const int* __restrict__ mask, const float* __restrict__ adj,
    const float* __restrict__ dist, const float* __restrict__ cw,
    const float* __restrict__ cb, float* __restrict__ comb, int n)
{
    const float w1 = cw[1], w2 = cw[2], b0 = cb[0];
    for (int i = blockIdx.x * 256 + threadIdx.x; i < n; i += gridDim.x * 256) {
        float c = -1e9f;
        if (mask[i] == 0) c = fmaf(w2, adj[i], fmaf(w1, __expf(-dist[i]), b0));
        comb[i] = c;
    }
}

// ---------------------------------------------------------------------------
// Projection GEMM (unchanged this round): C[m,n] = sum_d X[m,d] * W[n,d]
// ---------------------------------------------------------------------------
__global__ __launch_bounds__(256) void proj_qkv_kernel(
    const float* __restrict__ xq, const float* __restrict__ xk, const float* __restrict__ xv,
    const float* __restrict__ wqp, const float* __restrict__ wkp, const float* __restrict__ wvp,
    short* __restrict__ Qp, short* __restrict__ Kp, short* __restrict__ VpT)
{
    __shared__ __align__(16) short Alds[128 * 64];
    __shared__ __align__(16) short Blds[128 * 64];

    const int z = blockIdx.z;
    const float* X = (z == 0) ? xq : (z == 1) ? xk : xv;
    const float* W = (z == 0) ? wqp : (z == 1) ? wkp : wvp;

    const int tid = threadIdx.x;
    const int lane = tid & 63, wid = tid >> 6;
    const int l15 = lane & 15, lg = lane >> 4;
    const int m0 = blockIdx.y * 128, n0 = blockIdx.x * 128;
    const int wm = wid >> 1, wn = wid & 1;

    f32x4 acc[4][4] = {};

    for (int k0 = 0; k0 < D_; k0 += 64) {
        #pragma unroll
        for (int g = 0; g < 4; ++g) {
            const int c = g * 256 + tid;
            const int row = c >> 3, cc = c & 7;
            const int swc = cc ^ (row & 7);
            const float* ga = X + (size_t)(m0 + row) * D_ + k0 + cc * 8;
            float4v a0 = *(const float4v*)ga;
            float4v a1 = *(const float4v*)(ga + 4);
            *(bf16x8*)&Alds[(row * 8 + swc) * 8] = pack8(a0, a1);
            const float* gb = W + (size_t)(n0 + row) * D_ + k0 + cc * 8;
            float4v b0v = *(const float4v*)gb;
            float4v b1v = *(const float4v*)(gb + 4);
            *(bf16x8*)&Blds[(row * 8 + swc) * 8] = pack8(b0v, b1v);
        }
        __syncthreads();
        #pragma unroll
        for (int ks = 0; ks < 2; ++ks) {
            bf16x8 af[4], bfr[4];
            #pragma unroll
            for (int i = 0; i < 4; ++i) {
                const int row = wm * 64 + i * 16 + l15;
                af[i] = *(const bf16x8*)&Alds[(row * 8 + ((ks * 4 + lg) ^ (row & 7))) * 8];
            }
            #pragma unroll
            for (int j = 0; j < 4; ++j) {
                const int row = wn * 64 + j * 16 + l15;
                bfr[j] = *(const bf16x8*)&Blds[(row * 8 + ((ks * 4 + lg) ^ (row & 7))) * 8];
            }
            #pragma unroll
            for (int i = 0; i < 4; ++i)
                #pragma unroll
                for (int j = 0; j < 4; ++j)
                    acc[i][j] = mfma_bf16(af[i], bfr[j], acc[i][j]);
        }
        __syncthreads();
    }

    if (z < 2) {
        short* Outp = (z == 0) ? Qp : Kp;
        #pragma unroll
        for (int i = 0; i < 4; ++i) {
            #pragma unroll
            for (int j = 0; j < 4; ++j) {
                const int n = n0 + wn * 64 + j * 16 + l15;
                const int h = n >> 6, dk = n & 63;
                #pragma unroll
                for (int r = 0; r < 4; ++r) {
                    const int m = m0 + wm * 64 + i * 16 + lg * 4 + r;
                    const int b = m >> 9, s = m & 511;
                    Outp[((size_t)(b * H_ + h) * S_ + s) * DK_ + dk] = f2bf(acc[i][j][r]);
                }
            }
        }
    } else {
        #pragma unroll
        for (int i = 0; i < 4; ++i) {
            const int mb = m0 + wm * 64 + i * 16 + lg * 4;
            const int b = mb >> 9, s0v = mb & 511;
            #pragma unroll
            for (int j = 0; j < 4; ++j) {
                const int n = n0 + wn * 64 + j * 16 + l15;
                const int h = n >> 6, dk = n & 63;
                short4v v;
                #pragma unroll
                for (int r = 0; r < 4; ++r) v[r] = f2bf(acc[i][j][r]);
                *(short4v*)&VpT[((size_t)(b * H_ + h) * DK_ + dk) * S_ + s0v] = v;
            }
        }
    }
}

// ---------------------------------------------------------------------------
// Fused attention, 4-wave cooperative blocks.
// Block = 256 threads = 4 waves; one q-tile (16 rows) per block; wave w owns
// k in [w*128, w*128+128). comb cached in registers (no pass-C reload).
// Cross-wave softmax combines via 1KB LDS; per-wave 4KB P-transpose chunks,
// aliased afterwards as the cross-wave context-reduce buffer.
// Flat grid with b = id&7 so each batch's comb/K/V live in one XCD's L2.
// ---------------------------------------------------------------------------
__global__ __launch_bounds__(256, 4) void attn_kernel(
    const short* __restrict__ Qp, const short* __restrict__ Kp,
    const short* __restrict__ VpT, const float* __restrict__ comb,
    const float* __restrict__ cw, float* __restrict__ attn_out,
    short* __restrict__ Ctx)
{
    __shared__ __align__(16) char smem[16 * 1024 + 1024];
    float* red = (float*)(smem + 16384);   // 4 stages x [4 waves][16 rows]

    const int tid = threadIdx.x;
    const int lane = tid & 63, w = tid >> 6;
    const int l15 = lane & 15, lg = lane >> 4;

    const int id = blockIdx.x;
    const int b = id & 7;
    const int rest = id >> 3;
    const int qt = rest & 31, h = rest >> 5;
    const int bh = b * H_ + h;
    const int q0 = qt * 16;
    const int k0 = w * 128;

    const short* Qb = Qp + (size_t)bh * S_ * DK_;
    const short* Kb = Kp + (size_t)bh * S_ * DK_ + (size_t)k0 * DK_;
    const short* Vb = VpT + (size_t)bh * DK_ * S_;
    const float* cbm = comb + (size_t)b * S_ * S_ + (size_t)q0 * S_ + k0;
    const float w0 = cw[0];

    // Q A-fragments (same for all 4 waves; L1/L2 hit)
    bf16x8 aq0 = *(const bf16x8*)(Qb + (q0 + l15) * DK_ + lg * 8);
    bf16x8 aq1 = *(const bf16x8*)(Qb + (q0 + l15) * DK_ + 32 + lg * 8);

    // comb slice for this wave's k-chunk -> registers (reused in pass C)
    f32x4 cmb[8];
    #pragma unroll
    for (int nf = 0; nf < 8; ++nf)
        #pragma unroll
        for (int r = 0; r < 4; ++r)
            cmb[nf][r] = cbm[(size_t)(lg * 4 + r) * S_ + nf * 16 + l15];

    // QK^T for this wave's 128 k-columns
    f32x4 sc[8];
    #pragma unroll
    for (int nf = 0; nf < 8; ++nf) {
        bf16x8 bk0 = *(const bf16x8*)(Kb + (nf * 16 + l15) * DK_ + lg * 8);
        bf16x8 bk1 = *(const bf16x8*)(Kb + (nf * 16 + l15) * DK_ + 32 + lg * 8);
        f32x4 a = {};
        a = mfma_bf16(aq0, bk0, a);
        a = mfma_bf16(aq1, bk1, a);
        sc[nf] = a;
    }

    // ---- pass A: scale + mask, row max (in-wave then cross-wave) ----
    f32x4 mx;
    mx[0] = mx[1] = mx[2] = mx[3] = -3e38f;
    #pragma unroll
    for (int nf = 0; nf < 8; ++nf)
        #pragma unroll
        for (int r = 0; r < 4; ++r) {
            const float v = (cmb[nf][r] < -1e8f) ? -1e9f : sc[nf][r] * 0.125f;
            sc[nf][r] = v;
            mx[r] = fmaxf(mx[r], v);
        }
    #pragma unroll
    for (int off = 1; off < 16; off <<= 1)
        #pragma unroll
        for (int r = 0; r < 4; ++r)
            mx[r] = fmaxf(mx[r], __shfl_xor(mx[r], off));
    {
        float* rd = red;
        if (l15 == 0) {
            #pragma unroll
            for (int r = 0; r < 4; ++r) rd[w * 16 + lg * 4 + r] = mx[r];
        }
        __syncthreads();
        #pragma unroll
        for (int r = 0; r < 4; ++r) {
            const int row = lg * 4 + r;
            mx[r] = fmaxf(fmaxf(rd[row], rd[16 + row]), fmaxf(rd[32 + row], rd[48 + row]));
        }
    }

    // ---- pass B: exp + row sum -> softmax-1 ----
    f32x4 sm = {};
    #pragma unroll
    for (int nf = 0; nf < 8; ++nf)
        #pragma unroll
        for (int r = 0; r < 4; ++r) {
            const float e = __expf(sc[nf][r] - mx[r]);
            sc[nf][r] = e;
            sm[r] += e;
        }
    #pragma unroll
    for (int off = 1; off < 16; off <<= 1)
        #pragma unroll
        for (int r = 0; r < 4; ++r)
            sm[r] += __shfl_xor(sm[r], off);
    {
        float* rd = red + 64;
        if (l15 == 0) {
            #pragma unroll
            for (int r = 0; r < 4; ++r) rd[w * 16 + lg * 4 + r] = sm[r];
        }
        __syncthreads();
        #pragma unroll
        for (int r = 0; r < 4; ++r) {
            const int row = lg * 4 + r;
            sm[r] = (rd[row] + rd[16 + row]) + (rd[32 + row] + rd[48 + row]);
        }
    }
    f32x4 rs1;
    #pragma unroll
    for (int r = 0; r < 4; ++r) rs1[r] = 1.0f / sm[r];

    // ---- pass C: weighted = w0*p + comb (regs), max ----
    f32x4 mx2;
    mx2[0] = mx2[1] = mx2[2] = mx2[3] = -3e38f;
    #pragma unroll
    for (int nf = 0; nf < 8; ++nf)
        #pragma unroll
        for (int r = 0; r < 4; ++r) {
            const float p = sc[nf][r] * rs1[r];
            const float wv = fmaf(w0, p, cmb[nf][r]);
            sc[nf][r] = wv;
            mx2[r] = fmaxf(mx2[r], wv);
        }
    #pragma unroll
    for (int off = 1; off < 16; off <<= 1)
        #pragma unroll
        for (int r = 0; r < 4; ++r)
            mx2[r] = fmaxf(mx2[r], __shfl_xor(mx2[r], off));
    {
        float* rd = red + 128;
        if (l15 == 0) {
            #pragma unroll
            for (int r = 0; r < 4; ++r) rd[w * 16 + lg * 4 + r] = mx2[r];
        }
        __syncthreads();
        #pragma unroll
        for (int r = 0; r < 4; ++r) {
            const int row = lg * 4 + r;
            mx2[r] = fmaxf(fmaxf(rd[row], rd[16 + row]), fmaxf(rd[32 + row], rd[48 + row]));
        }
    }

    // ---- pass D: exp + row sum -> softmax-2 ----
    f32x4 sm2 = {};
    #pragma unroll
    for (int nf = 0; nf < 8; ++nf)
        #pragma unroll
        for (int r = 0; r < 4; ++r) {
            const float e = __expf(sc[nf][r] - mx2[r]);
            sc[nf][r] = e;
            sm2[r] += e;
        }
    #pragma unroll
    for (int off = 1; off < 16; off <<= 1)
        #pragma unroll
        for (int r = 0; r < 4; ++r)
            sm2[r] += __shfl_xor(sm2[r], off);
    {
        float* rd = red + 192;
        if (l15 == 0) {
            #pragma unroll
            for (int r = 0; r < 4; ++r) rd[w * 16 + lg * 4 + r] = sm2[r];
        }
        __syncthreads();
        #pragma unroll
        for (int r = 0; r < 4; ++r) {
            const int row = lg * 4 + r;
            sm2[r] = (rd[row] + rd[16 + row]) + (rd[32 + row] + rd[48 + row]);
        }
    }
    f32x4 rs2;
    #pragma unroll
    for (int r = 0; r < 4; ++r) rs2[r] = 1.0f / sm2[r];

    // ---- pass E: write attn fp32, stage P bf16 (swizzled per-wave LDS) ----
    float* aout = attn_out + ((size_t)bh * S_ + q0) * S_ + k0;
    #pragma unroll
    for (int nf = 0; nf < 8; ++nf)
        #pragma unroll
        for (int r = 0; r < 4; ++r) {
            const int q = lg * 4 + r;
            const float av = sc[nf][r] * rs2[r];
            aout[(size_t)q * S_ + nf * 16 + l15] = av;
            const int byteo = ((q * 256 + (nf * 16 + l15) * 2) ^ ((q & 7) << 4)) + w * 4096;
            *(short*)(smem + byteo) = f2bf(av);
        }
    __syncthreads();

    // ---- PV over this wave's k-chunk ----
    f32x4 cacc[4] = {};
    #pragma unroll
    for (int ks = 0; ks < 4; ++ks) {
        const int byteA = ((l15 * 256 + (ks * 32 + lg * 8) * 2) ^ ((l15 & 7) << 4)) + w * 4096;
        bf16x8 pa = *(const bf16x8*)(smem + byteA);
        #pragma unroll
        for (int j = 0; j < 4; ++j) {
            bf16x8 bv = *(const bf16x8*)(Vb + (size_t)(j * 16 + l15) * S_ + k0 + ks * 32 + lg * 8);
            cacc[j] = mfma_bf16(pa, bv, cacc[j]);
        }
    }
    __syncthreads();   // all P reads done; alias smem as ctxred [4][16][64] f32

    float* cr = (float*)smem;
    #pragma unroll
    for (int j = 0; j < 4; ++j)
        #pragma unroll
        for (int r = 0; r < 4; ++r)
            cr[w * 1024 + (lg * 4 + r) * 64 + j * 16 + l15] = cacc[j][r];
    __syncthreads();

    // wave w reduces + writes d-block j = w
    #pragma unroll
    for (int r = 0; r < 4; ++r) {
        const int row = lg * 4 + r;
        const float v = (cr[row * 64 + w * 16 + l15] + cr[1024 + row * 64 + w * 16 + l15])
                      + (cr[2048 + row * 64 + w * 16 + l15] + cr[3072 + row * 64 + w * 16 + l15]);
        Ctx[(size_t)(b * S_ + q0 + row) * D_ + h * 64 + w * 16 + l15] = f2bf(v);
    }
}

// ---------------------------------------------------------------------------
// Output GEMM (unchanged this round)
// ---------------------------------------------------------------------------
__global__ __launch_bounds__(256) void fc_kernel(
    const short* __restrict__ Ctx, const float* __restrict__ Wfc,
    float* __restrict__ Out)
{
    __shared__ __align__(16) short Alds[128 * 64];
    __shared__ __align__(16) short Blds[128 * 64];

    const int tid = threadIdx.x;
    const int lane = tid & 63, wid = tid >> 6;
    const int l15 = lane & 15, lg = lane >> 4;
    const int m0 = blockIdx.y * 128, n0 = blockIdx.x * 128;
    const int wm = wid >> 1, wn = wid & 1;

    f32x4 acc[4][4] = {};

    for (int k0 = 0; k0 < D_; k0 += 64) {
        #pragma unroll
        for (int g = 0; g < 4; ++g) {
            const int c = g * 256 + tid;
            const int row = c >> 3, cc = c & 7;
            const int swc = cc ^ (row & 7);
            bf16x8 va = *(const bf16x8*)(Ctx + (size_t)(m0 + row) * D_ + k0 + cc * 8);
            *(bf16x8*)&Alds[(row * 8 + swc) * 8] = va;
            const float* gb = Wfc + (size_t)(n0 + row) * D_ + k0 + cc * 8;
            float4v b0v = *(const float4v*)gb;
            float4v b1v = *(const float4v*)(gb + 4);
            *(bf16x8*)&Blds[(row * 8 + swc) * 8] = pack8(b0v, b1v);
        }
        __syncthreads();
        #pragma unroll
        for (int ks = 0; ks < 2; ++ks) {
            bf16x8 af[4], bfr[4];
            #pragma unroll
            for (int i = 0; i < 4; ++i) {
                const int row = wm * 64 + i * 16 + l15;
                af[i] = *(const bf16x8*)&Alds[(row * 8 + ((ks * 4 + lg) ^ (row & 7))) * 8];
            }
            #pragma unroll
            for (int j = 0; j < 4; ++j) {
                const int row = wn * 64 + j * 16 + l15;
                bfr[j] = *(const bf16x8*)&Blds[(row * 8 + ((ks * 4 + lg) ^ (row & 7))) * 8];
            }
            #pragma unroll
            for (int i = 0; i < 4; ++i)
                #pragma unroll
                for (int j = 0; j < 4; ++j)
                    acc[i][j] = mfma_bf16(af[i], bfr[j], acc[i][j]);
        }
        __syncthreads();
    }

    #pragma unroll
    for (int i = 0; i < 4; ++i)
        #pragma unroll
        for (int j = 0; j < 4; ++j)
            #pragma unroll
            for (int r = 0; r < 4; ++r) {
                const int m = m0 + wm * 64 + i * 16 + lg * 4 + r;
                const int n = n0 + wn * 64 + j * 16 + l15;
                Out[(size_t)m * D_ + n] = acc[i][j][r];
            }
}

// ---------------------------------------------------------------------------
extern "C" void kernel_launch(void* const* d_in, const int* in_sizes, int n_in,
                              void* d_out, int out_size, void* d_ws, size_t ws_size,
                              hipStream_t stream) {
    const float* xq   = (const float*)d_in[0];
    const float* xk   = (const float*)d_in[1];
    const float* xv   = (const float*)d_in[2];
    const int*   mask = (const int*)d_in[3];
    const float* adj  = (const float*)d_in[4];
    const float* dist = (const float*)d_in[5];
    const float* wq   = (const float*)d_in[6];
    const float* wk   = (const float*)d_in[7];
    const float* wv   = (const float*)d_in[8];
    const float* wfc  = (const float*)d_in[9];
    const float* cw   = (const float*)d_in[10];
    const float* cb   = (const float*)d_in[11];

    float* out  = (float*)d_out;                       // (B,S,D) fp32
    float* attn = out + (size_t)B_ * S_ * D_;          // (B,H,S,S) fp32

    char* ws = (char*)d_ws;
    short* Qp   = (short*)(ws);                        // [B,H,S,DK] bf16
    short* Kp   = (short*)(ws + (8u  << 20));          // [B,H,S,DK] bf16
    short* VpT  = (short*)(ws + (16u << 20));          // [B,H,DK,S] bf16
    short* Ctx  = (short*)(ws + (24u << 20));          // [B*S, D]   bf16
    float* comb = (float*)(ws + (32u << 20));          // [B,S,S]    fp32

    precomp_kernel<<<dim3(1024), dim3(256), 0, stream>>>(
        mask, adj, dist, cw, cb, comb, B_ * S_ * S_);
    proj_qkv_kernel<<<dim3(8, 32, 3), dim3(256), 0, stream>>>(
        xq, xk, xv, wq, wk, wv, Qp, Kp, VpT);
    attn_kernel<<<dim3(4096), dim3(256), 0, stream>>>(
        Qp, Kp, VpT, comb, cw, attn, Ctx);
    fc_kernel<<<dim3(8, 32), dim3(256), 0, stream>>>(Ctx, wfc, out);
}

// Round 3
// 174.414 us; speedup vs baseline: 1.4260x; 1.2223x over previous
//
#include <hip/hip_runtime.h>
#include <stdint.h>

#define B_ 8
#define S_ 512
#define D_ 1024
#define H_ 16
#define DK_ 64

typedef float f32x4 __attribute__((ext_vector_type(4)));
typedef float float4v __attribute__((ext_vector_type(4)));
typedef short bf16x8 __attribute__((ext_vector_type(8)));
typedef short short4v __attribute__((ext_vector_type(4)));
typedef __bf16 bfv8 __attribute__((ext_vector_type(8)));

__device__ __forceinline__ short f2bf(float f) {
    return __builtin_bit_cast(short, (__bf16)f);
}

__device__ __forceinline__ f32x4 mfma_bf16(bf16x8 a, bf16x8 b, f32x4 c) {
    return __builtin_amdgcn_mfma_f32_16x16x32_bf16(
        __builtin_bit_cast(bfv8, a), __builtin_bit_cast(bfv8, b), c, 0, 0, 0);
}

__device__ __forceinline__ bf16x8 cvt8(float4v a, float4v b) {
    bf16x8 v;
    v[0] = f2bf(a[0]); v[1] = f2bf(a[1]); v[2] = f2bf(a[2]); v[3] = f2bf(a[3]);
    v[4] = f2bf(b[0]); v[5] = f2bf(b[1]); v[6] = f2bf(b[2]); v[7] = f2bf(b[3]);
    return v;
}

__device__ __forceinline__ void gl_lds16(const void* g, void* l) {
    __builtin_amdgcn_global_load_lds(
        (const __attribute__((address_space(1))) void*)g,
        (__attribute__((address_space(3))) void*)l, 16, 0, 0);
}

// ---------------------------------------------------------------------------
// Convert xq,xk,xv -> Xb bf16 [3][4096][1024]; wq,wk,wv,wfc -> Wb bf16 [4][1024][1024]
// ---------------------------------------------------------------------------
__global__ __launch_bounds__(256) void conv_all_kernel(
    const float* __restrict__ xq, const float* __restrict__ xk, const float* __restrict__ xv,
    const float* __restrict__ wq, const float* __restrict__ wk, const float* __restrict__ wv,
    const float* __restrict__ wfc, short* __restrict__ Xb, short* __restrict__ Wb)
{
    const int NX = 3 * 4096 * 1024;           // 12582912
    const int NTOT = NX + 4 * 1024 * 1024;    // 16777216
    for (int i = blockIdx.x * 256 + threadIdx.x; i * 8 < NTOT; i += gridDim.x * 256) {
        const int i8 = i * 8;
        const float* src;
        short* dst;
        if (i8 < NX) {
            const int z = i8 >> 22, off = i8 & ((1 << 22) - 1);
            src = ((z == 0) ? xq : (z == 1) ? xk : xv) + off;
            dst = Xb + i8;
        } else {
            const int j = i8 - NX;
            const int w = j >> 20, off = j & ((1 << 20) - 1);
            src = ((w == 0) ? wq : (w == 1) ? wk : (w == 2) ? wv : wfc) + off;
            dst = Wb + i8 - NX;
        }
        float4v a = *(const float4v*)src;
        float4v b = *(const float4v*)(src + 4);
        *(bf16x8*)dst = cvt8(a, b);
    }
}

// ---------------------------------------------------------------------------
// comb[b,q,k] = mask ? -1e9 : w1*exp(-dist) + w2*adj + b0
// ---------------------------------------------------------------------------
__global__ __launch_bounds__(256) void precomp_kernel(
    const int* __restrict__ mask, const float* __restrict__ adj,
    const float* __restrict__ dist, const float* __restrict__ cw,
    const float* __restrict__ cb, float* __restrict__ comb, int n)
{
    const float w1 = cw[1], w2 = cw[2], b0 = cb[0];
    for (int i = blockIdx.x * 256 + threadIdx.x; i < n; i += gridDim.x * 256) {
        float c = -1e9f;
        if (mask[i] == 0) c = fmaf(w2, adj[i], fmaf(w1, __expf(-dist[i]), b0));
        comb[i] = c;
    }
}

// ---------------------------------------------------------------------------
// Projection GEMM, bf16 in: C[m,n] = sum_d X[m,d] * W[n,d]
// m97 structure: global_load_lds width 16, pre-swizzled global source
// (chunk ^ (row&7)), linear LDS dest, swizzled ds_read_b128 frags.
// XCD-bijective block swizzle: all 8 n-tiles of an m-row on one XCD.
// ---------------------------------------------------------------------------
__global__ __launch_bounds__(256) void proj_qkv_kernel(
    const short* __restrict__ Xb, const short* __restrict__ Wb,
    short* __restrict__ Qp, short* __restrict__ Kp, short* __restrict__ VpT)
{
    __shared__ __align__(16) short Alds[128 * 64];
    __shared__ __align__(16) short Blds[128 * 64];

    const int z = blockIdx.z;
    const short* X = Xb + (size_t)z * (4096 * 1024);
    const short* W = Wb + (size_t)z * (1024 * 1024);

    const int tid = threadIdx.x;
    const int lane = tid & 63, w = tid >> 6;
    const int l15 = lane & 15, lg = lane >> 4;

    const int p = blockIdx.x;                     // 0..255
    const int lin = (p & 7) * 32 + (p >> 3);      // bijective XCD swizzle
    const int n0 = (lin & 7) * 128, m0 = (lin >> 3) * 128;
    const int wm = w >> 1, wn = w & 1;

    f32x4 acc[4][4] = {};

    for (int k0 = 0; k0 < D_; k0 += 64) {
        #pragma unroll
        for (int t = 0; t < 4; ++t) {
            const int r0 = w * 32 + t * 8;
            const int row = r0 + (lane >> 3);
            const int sc = (lane & 7) ^ (row & 7);
            gl_lds16(X + (size_t)(m0 + row) * D_ + k0 + sc * 8, &Alds[r0 * 64]);
            gl_lds16(W + (size_t)(n0 + row) * D_ + k0 + sc * 8, &Blds[r0 * 64]);
        }
        __syncthreads();
        #pragma unroll
        for (int ks = 0; ks < 2; ++ks) {
            bf16x8 af[4], bfr[4];
            #pragma unroll
            for (int i = 0; i < 4; ++i) {
                const int row = wm * 64 + i * 16 + l15;
                af[i] = *(const bf16x8*)&Alds[(row * 8 + ((ks * 4 + lg) ^ (row & 7))) * 8];
            }
            #pragma unroll
            for (int j = 0; j < 4; ++j) {
                const int row = wn * 64 + j * 16 + l15;
                bfr[j] = *(const bf16x8*)&Blds[(row * 8 + ((ks * 4 + lg) ^ (row & 7))) * 8];
            }
            #pragma unroll
            for (int i = 0; i < 4; ++i)
                #pragma unroll
                for (int j = 0; j < 4; ++j)
                    acc[i][j] = mfma_bf16(af[i], bfr[j], acc[i][j]);
        }
        __syncthreads();
    }

    if (z < 2) {
        short* Outp = (z == 0) ? Qp : Kp;
        #pragma unroll
        for (int i = 0; i < 4; ++i) {
            #pragma unroll
            for (int j = 0; j < 4; ++j) {
                const int n = n0 + wn * 64 + j * 16 + l15;
                const int h = n >> 6, dk = n & 63;
                #pragma unroll
                for (int r = 0; r < 4; ++r) {
                    const int m = m0 + wm * 64 + i * 16 + lg * 4 + r;
                    const int b = m >> 9, s = m & 511;
                    Outp[((size_t)(b * H_ + h) * S_ + s) * DK_ + dk] = f2bf(acc[i][j][r]);
                }
            }
        }
    } else {
        #pragma unroll
        for (int i = 0; i < 4; ++i) {
            const int mb = m0 + wm * 64 + i * 16 + lg * 4;
            const int b = mb >> 9, s0v = mb & 511;
            #pragma unroll
            for (int j = 0; j < 4; ++j) {
                const int n = n0 + wn * 64 + j * 16 + l15;
                const int h = n >> 6, dk = n & 63;
                short4v v;
                #pragma unroll
                for (int r = 0; r < 4; ++r) v[r] = f2bf(acc[i][j][r]);
                *(short4v*)&VpT[((size_t)(b * H_ + h) * DK_ + dk) * S_ + s0v] = v;
            }
        }
    }
}

// ---------------------------------------------------------------------------
// Fused attention, 4-wave cooperative blocks (unchanged from round 2).
// ---------------------------------------------------------------------------
__global__ __launch_bounds__(256, 4) void attn_kernel(
    const short* __restrict__ Qp, const short* __restrict__ Kp,
    const short* __restrict__ VpT, const float* __restrict__ comb,
    const float* __restrict__ cw, float* __restrict__ attn_out,
    short* __restrict__ Ctx)
{
    __shared__ __align__(16) char smem[16 * 1024 + 1024];
    float* red = (float*)(smem + 16384);

    const int tid = threadIdx.x;
    const int lane = tid & 63, w = tid >> 6;
    const int l15 = lane & 15, lg = lane >> 4;

    const int id = blockIdx.x;
    const int b = id & 7;
    const int rest = id >> 3;
    const int qt = rest & 31, h = rest >> 5;
    const int bh = b * H_ + h;
    const int q0 = qt * 16;
    const int k0 = w * 128;

    const short* Qb = Qp + (size_t)bh * S_ * DK_;
    const short* Kb = Kp + (size_t)bh * S_ * DK_ + (size_t)k0 * DK_;
    const short* Vb = VpT + (size_t)bh * DK_ * S_;
    const float* cbm = comb + (size_t)b * S_ * S_ + (size_t)q0 * S_ + k0;
    const float w0 = cw[0];

    bf16x8 aq0 = *(const bf16x8*)(Qb + (q0 + l15) * DK_ + lg * 8);
    bf16x8 aq1 = *(const bf16x8*)(Qb + (q0 + l15) * DK_ + 32 + lg * 8);

    f32x4 cmb[8];
    #pragma unroll
    for (int nf = 0; nf < 8; ++nf)
        #pragma unroll
        for (int r = 0; r < 4; ++r)
            cmb[nf][r] = cbm[(size_t)(lg * 4 + r) * S_ + nf * 16 + l15];

    f32x4 sc[8];
    #pragma unroll
    for (int nf = 0; nf < 8; ++nf) {
        bf16x8 bk0 = *(const bf16x8*)(Kb + (nf * 16 + l15) * DK_ + lg * 8);
        bf16x8 bk1 = *(const bf16x8*)(Kb + (nf * 16 + l15) * DK_ + 32 + lg * 8);
        f32x4 a = {};
        a = mfma_bf16(aq0, bk0, a);
        a = mfma_bf16(aq1, bk1, a);
        sc[nf] = a;
    }

    // pass A
    f32x4 mx;
    mx[0] = mx[1] = mx[2] = mx[3] = -3e38f;
    #pragma unroll
    for (int nf = 0; nf < 8; ++nf)
        #pragma unroll
        for (int r = 0; r < 4; ++r) {
            const float v = (cmb[nf][r] < -1e8f) ? -1e9f : sc[nf][r] * 0.125f;
            sc[nf][r] = v;
            mx[r] = fmaxf(mx[r], v);
        }
    #pragma unroll
    for (int off = 1; off < 16; off <<= 1)
        #pragma unroll
        for (int r = 0; r < 4; ++r)
            mx[r] = fmaxf(mx[r], __shfl_xor(mx[r], off));
    {
        float* rd = red;
        if (l15 == 0) {
            #pragma unroll
            for (int r = 0; r < 4; ++r) rd[w * 16 + lg * 4 + r] = mx[r];
        }
        __syncthreads();
        #pragma unroll
        for (int r = 0; r < 4; ++r) {
            const int row = lg * 4 + r;
            mx[r] = fmaxf(fmaxf(rd[row], rd[16 + row]), fmaxf(rd[32 + row], rd[48 + row]));
        }
    }

    // pass B
    f32x4 sm = {};
    #pragma unroll
    for (int nf = 0; nf < 8; ++nf)
        #pragma unroll
        for (int r = 0; r < 4; ++r) {
            const float e = __expf(sc[nf][r] - mx[r]);
            sc[nf][r] = e;
            sm[r] += e;
        }
    #pragma unroll
    for (int off = 1; off < 16; off <<= 1)
        #pragma unroll
        for (int r = 0; r < 4; ++r)
            sm[r] += __shfl_xor(sm[r], off);
    {
        float* rd = red + 64;
        if (l15 == 0) {
            #pragma unroll
            for (int r = 0; r < 4; ++r) rd[w * 16 + lg * 4 + r] = sm[r];
        }
        __syncthreads();
        #pragma unroll
        for (int r = 0; r < 4; ++r) {
            const int row = lg * 4 + r;
            sm[r] = (rd[row] + rd[16 + row]) + (rd[32 + row] + rd[48 + row]);
        }
    }
    f32x4 rs1;
    #pragma unroll
    for (int r = 0; r < 4; ++r) rs1[r] = 1.0f / sm[r];

    // pass C
    f32x4 mx2;
    mx2[0] = mx2[1] = mx2[2] = mx2[3] = -3e38f;
    #pragma unroll
    for (int nf = 0; nf < 8; ++nf)
        #pragma unroll
        for (int r = 0; r < 4; ++r) {
            const float pv = sc[nf][r] * rs1[r];
            const float wv = fmaf(w0, pv, cmb[nf][r]);
            sc[nf][r] = wv;
            mx2[r] = fmaxf(mx2[r], wv);
        }
    #pragma unroll
    for (int off = 1; off < 16; off <<= 1)
        #pragma unroll
        for (int r = 0; r < 4; ++r)
            mx2[r] = fmaxf(mx2[r], __shfl_xor(mx2[r], off));
    {
        float* rd = red + 128;
        if (l15 == 0) {
            #pragma unroll
            for (int r = 0; r < 4; ++r) rd[w * 16 + lg * 4 + r] = mx2[r];
        }
        __syncthreads();
        #pragma unroll
        for (int r = 0; r < 4; ++r) {
            const int row = lg * 4 + r;
            mx2[r] = fmaxf(fmaxf(rd[row], rd[16 + row]), fmaxf(rd[32 + row], rd[48 + row]));
        }
    }

    // pass D
    f32x4 sm2 = {};
    #pragma unroll
    for (int nf = 0; nf < 8; ++nf)
        #pragma unroll
        for (int r = 0; r < 4; ++r) {
            const float e = __expf(sc[nf][r] - mx2[r]);
            sc[nf][r] = e;
            sm2[r] += e;
        }
    #pragma unroll
    for (int off = 1; off < 16; off <<= 1)
        #pragma unroll
        for (int r = 0; r < 4; ++r)
            sm2[r] += __shfl_xor(sm2[r], off);
    {
        float* rd = red + 192;
        if (l15 == 0) {
            #pragma unroll
            for (int r = 0; r < 4; ++r) rd[w * 16 + lg * 4 + r] = sm2[r];
        }
        __syncthreads();
        #pragma unroll
        for (int r = 0; r < 4; ++r) {
            const int row = lg * 4 + r;
            sm2[r] = (rd[row] + rd[16 + row]) + (rd[32 + row] + rd[48 + row]);
        }
    }
    f32x4 rs2;
    #pragma unroll
    for (int r = 0; r < 4; ++r) rs2[r] = 1.0f / sm2[r];

    // pass E
    float* aout = attn_out + ((size_t)bh * S_ + q0) * S_ + k0;
    #pragma unroll
    for (int nf = 0; nf < 8; ++nf)
        #pragma unroll
        for (int r = 0; r < 4; ++r) {
            const int q = lg * 4 + r;
            const float av = sc[nf][r] * rs2[r];
            aout[(size_t)q * S_ + nf * 16 + l15] = av;
            const int byteo = ((q * 256 + (nf * 16 + l15) * 2) ^ ((q & 7) << 4)) + w * 4096;
            *(short*)(smem + byteo) = f2bf(av);
        }
    __syncthreads();

    f32x4 cacc[4] = {};
    #pragma unroll
    for (int ks = 0; ks < 4; ++ks) {
        const int byteA = ((l15 * 256 + (ks * 32 + lg * 8) * 2) ^ ((l15 & 7) << 4)) + w * 4096;
        bf16x8 pa = *(const bf16x8*)(smem + byteA);
        #pragma unroll
        for (int j = 0; j < 4; ++j) {
            bf16x8 bv = *(const bf16x8*)(Vb + (size_t)(j * 16 + l15) * S_ + k0 + ks * 32 + lg * 8);
            cacc[j] = mfma_bf16(pa, bv, cacc[j]);
        }
    }
    __syncthreads();

    float* cr = (float*)smem;
    #pragma unroll
    for (int j = 0; j < 4; ++j)
        #pragma unroll
        for (int r = 0; r < 4; ++r)
            cr[w * 1024 + (lg * 4 + r) * 64 + j * 16 + l15] = cacc[j][r];
    __syncthreads();

    #pragma unroll
    for (int r = 0; r < 4; ++r) {
        const int row = lg * 4 + r;
        const float v = (cr[row * 64 + w * 16 + l15] + cr[1024 + row * 64 + w * 16 + l15])
                      + (cr[2048 + row * 64 + w * 16 + l15] + cr[3072 + row * 64 + w * 16 + l15]);
        Ctx[(size_t)(b * S_ + q0 + row) * D_ + h * 64 + w * 16 + l15] = f2bf(v);
    }
}

// ---------------------------------------------------------------------------
// Output GEMM, bf16 in / fp32 out: Out[m,n] = sum_d Ctx[m,d] * Wfc[n,d]
// Same m97 structure as proj.
// ---------------------------------------------------------------------------
__global__ __launch_bounds__(256) void fc_kernel(
    const short* __restrict__ Ctx, const short* __restrict__ Wfcb,
    float* __restrict__ Out)
{
    __shared__ __align__(16) short Alds[128 * 64];
    __shared__ __align__(16) short Blds[128 * 64];

    const int tid = threadIdx.x;
    const int lane = tid & 63, w = tid >> 6;
    const int l15 = lane & 15, lg = lane >> 4;

    const int p = blockIdx.x;
    const int lin = (p & 7) * 32 + (p >> 3);
    const int n0 = (lin & 7) * 128, m0 = (lin >> 3) * 128;
    const int wm = w >> 1, wn = w & 1;

    f32x4 acc[4][4] = {};

    for (int k0 = 0; k0 < D_; k0 += 64) {
        #pragma unroll
        for (int t = 0; t < 4; ++t) {
            const int r0 = w * 32 + t * 8;
            const int row = r0 + (lane >> 3);
            const int sc = (lane & 7) ^ (row & 7);
            gl_lds16(Ctx + (size_t)(m0 + row) * D_ + k0 + sc * 8, &Alds[r0 * 64]);
            gl_lds16(Wfcb + (size_t)(n0 + row) * D_ + k0 + sc * 8, &Blds[r0 * 64]);
        }
        __syncthreads();
        #pragma unroll
        for (int ks = 0; ks < 2; ++ks) {
            bf16x8 af[4], bfr[4];
            #pragma unroll
            for (int i = 0; i < 4; ++i) {
                const int row = wm * 64 + i * 16 + l15;
                af[i] = *(const bf16x8*)&Alds[(row * 8 + ((ks * 4 + lg) ^ (row & 7))) * 8];
            }
            #pragma unroll
            for (int j = 0; j < 4; ++j) {
                const int row = wn * 64 + j * 16 + l15;
                bfr[j] = *(const bf16x8*)&Blds[(row * 8 + ((ks * 4 + lg) ^ (row & 7))) * 8];
            }
            #pragma unroll
            for (int i = 0; i < 4; ++i)
                #pragma unroll
                for (int j = 0; j < 4; ++j)
                    acc[i][j] = mfma_bf16(af[i], bfr[j], acc[i][j]);
        }
        __syncthreads();
    }

    #pragma unroll
    for (int i = 0; i < 4; ++i)
        #pragma unroll
        for (int j = 0; j < 4; ++j)
            #pragma unroll
            for (int r = 0; r < 4; ++r) {
                const int m = m0 + wm * 64 + i * 16 + lg * 4 + r;
                const int n = n0 + wn * 64 + j * 16 + l15;
                Out[(size_t)m * D_ + n] = acc[i][j][r];
            }
}

// ---------------------------------------------------------------------------
extern "C" void kernel_launch(void* const* d_in, const int* in_sizes, int n_in,
                              void* d_out, int out_size, void* d_ws, size_t ws_size,
                              hipStream_t stream) {
    const float* xq   = (const float*)d_in[0];
    const float* xk   = (const float*)d_in[1];
    const float* xv   = (const float*)d_in[2];
    const int*   mask = (const int*)d_in[3];
    const float* adj  = (const float*)d_in[4];
    const float* dist = (const float*)d_in[5];
    const float* wq   = (const float*)d_in[6];
    const float* wk   = (const float*)d_in[7];
    const float* wv   = (const float*)d_in[8];
    const float* wfc  = (const float*)d_in[9];
    const float* cw   = (const float*)d_in[10];
    const float* cb   = (const float*)d_in[11];

    float* out  = (float*)d_out;                       // (B,S,D) fp32
    float* attn = out + (size_t)B_ * S_ * D_;          // (B,H,S,S) fp32

    // ws layout (56 MB):
    //  [0,24M)   Xb bf16 [3][4096][1024]   (dead after proj)
    //    [0,8.4M)  comb fp32 (aliases Xb; written AFTER proj)
    //    [9M,17M)  Ctx bf16  (aliases Xb; written by attn)
    //  [24M,32M) Wb bf16 [4][1024][1024]
    //  [32M,40M) Qp  [40M,48M) Kp  [48M,56M) VpT
    char* ws = (char*)d_ws;
    short* Xb   = (short*)(ws);
    float* comb = (float*)(ws);
    short* Ctx  = (short*)(ws + (9u << 20));
    short* Wb   = (short*)(ws + (24u << 20));
    short* Qp   = (short*)(ws + (32u << 20));
    short* Kp   = (short*)(ws + (40u << 20));
    short* VpT  = (short*)(ws + (48u << 20));
    const short* Wfcb = Wb + (size_t)3 * 1024 * 1024;

    conv_all_kernel<<<dim3(2048), dim3(256), 0, stream>>>(
        xq, xk, xv, wq, wk, wv, wfc, Xb, Wb);
    proj_qkv_kernel<<<dim3(256, 1, 3), dim3(256), 0, stream>>>(
        Xb, Wb, Qp, Kp, VpT);
    precomp_kernel<<<dim3(1024), dim3(256), 0, stream>>>(
        mask, adj, dist, cw, cb, comb, B_ * S_ * S_);
    attn_kernel<<<dim3(4096), dim3(256), 0, stream>>>(
        Qp, Kp, VpT, comb, cw, attn, Ctx);
    fc_kernel<<<dim3(256), dim3(256), 0, stream>>>(Ctx, Wfcb, out);
}